// Round 4
// baseline (264.312 us; speedup 1.0000x reference)
//
#include <hip/hip_runtime.h>
#include <stdint.h>
#include <math.h>

#define HH 256
#define WW 256
#define BATCH 16
#define HP 257            // pooled field is 257x257
#define SROW 264          // padded row stride
#define SH 259            // padded rows (1 zero row top/bottom)
#define SBP (SH*SROW)     // per-batch padded s size
#define TS 32             // phase-A tile core
#define TH 9              // tiles per dim
#define NT (TH*TH)        // 81 tiles per batch
#define NTILES (BATCH*NT) // 1296
#define NVB 512           // virtual blocks for phases B and C

struct SA { float xs[35][36]; float sh[34][35]; float redmn[4][8]; float redmx[4][8]; };
struct SB { float lh[4*64*32]; float band[11][260]; };
struct SC { float hloc[4*3584]; float w9l[4*9*56]; float wfl[144]; float wred[4][16];
            float gmn[8]; float gmx[8]; float gstat[8]; float sred[4]; };
union  SU { SA a; SB b; SC c; };   // ~66.4 KB -> 2 blocks/CU (<= 80 KB)

__device__ __forceinline__ float leaky(float v){ return v >= 0.f ? v : 0.01f*v; }

// group k (0..3) channel-0 offset; channel 1 uses the negation.
__device__ __forceinline__ void group_off(int k, int& dh, int& dw){
    dh = (k == 3) ? 0 : -1;
    dw = (k == 3) ? 1 : (k - 1);
}

// Device-scope semaphore barrier. bar[slot*2] = arrive count, bar[slot*2+1] = release flag.
// Counters zeroed host-side via hipMemsetAsync before launch. Safe iff all nblk blocks resident.
__device__ __forceinline__ void grid_barrier(unsigned* bar, int slot, int nblk){
    __syncthreads();
    if (threadIdx.x == 0){
        __threadfence();
        unsigned prev = __hip_atomic_fetch_add(&bar[slot*2], 1u, __ATOMIC_ACQ_REL,
                                               __HIP_MEMORY_SCOPE_AGENT);
        if (prev + 1u == (unsigned)nblk){
            __hip_atomic_store(&bar[slot*2+1], 1u, __ATOMIC_RELEASE, __HIP_MEMORY_SCOPE_AGENT);
        } else {
            while (__hip_atomic_load(&bar[slot*2+1], __ATOMIC_ACQUIRE,
                                     __HIP_MEMORY_SCOPE_AGENT) == 0u)
                __builtin_amdgcn_s_sleep(2);
        }
        __threadfence();
    }
    __syncthreads();
}

// ---- Phase A: one pool->s tile + 8-diff minmax partials ----
__device__ void phaseA_tile(SA& A, int blk, const float* __restrict__ x, float* __restrict__ s,
                            float* __restrict__ pmn, float* __restrict__ pmx, float* __restrict__ hist)
{
    int tid = threadIdx.x, wv = tid >> 6, lane = tid & 63;
    int b = blk / NT, tile = blk % NT;
    int ty = tile / TH, tx = tile % TH;

    if (blk == 0){
        for (int t = tid; t < 4096; t += 256) hist[t] = 0.f;
    }
    if (blk < BATCH){
        float* sb = s + (size_t)blk*SBP;
        for (int t = tid; t < 2*SROW; t += 256){
            int rr = (t < SROW) ? 0 : 258; int cc = t % SROW;
            sb[rr*SROW + cc] = 0.f;
        }
        for (int t = tid; t < 257*7; t += 256){
            int rr = 1 + t/7, k = t%7;
            int cc = (k == 0) ? 0 : (257 + k);
            sb[rr*SROW + cc] = 0.f;
        }
    }

    const float* xb = x + (size_t)b*3*HH*WW;
    int xr0 = ty*TS - 2, xc0 = tx*TS - 2;
    for (int t = tid; t < 35*35; t += 256){
        int i = t/35, j = t - i*35;
        int r = xr0 + i, c = xc0 + j;
        float v = 0.f;
        if ((unsigned)r < (unsigned)HH && (unsigned)c < (unsigned)WW){
            int o = r*WW + c;
            v = xb[o] + xb[HH*WW + o] + xb[2*HH*WW + o];
        }
        A.xs[i][j] = v;
    }
    __syncthreads();

    for (int t = tid; t < 34*34; t += 256){
        int i = t/34, j = t - i*34;
        int h = ty*TS - 1 + i, w = tx*TS - 1 + j;
        float v = 0.f;
        if ((unsigned)h < (unsigned)HP && (unsigned)w < (unsigned)HP)
            v = 0.25f*(A.xs[i][j] + A.xs[i][j+1] + A.xs[i+1][j] + A.xs[i+1][j+1]);
        A.sh[i][j] = v;
    }
    __syncthreads();

    float mn[8], mx[8];
    #pragma unroll
    for (int q=0;q<8;q++){ mn[q]=INFINITY; mx[q]=-INFINITY; }
    float* sb = s + (size_t)b*SBP;
    #pragma unroll
    for (int q4=0; q4<4; ++q4){
        int p = q4*256 + tid;
        int lr = p >> 5, lc = p & 31;
        int h = ty*TS + lr, w = tx*TS + lc;
        if (h < HP && w < HP){
            float c = A.sh[lr+1][lc+1];
            sb[(h+1)*SROW + (w+1)] = c;
            float d;
            d = c - A.sh[lr  ][lc  ]; mn[0]=fminf(mn[0],d); mx[0]=fmaxf(mx[0],d);
            d = c - A.sh[lr+2][lc+2]; mn[1]=fminf(mn[1],d); mx[1]=fmaxf(mx[1],d);
            d = c - A.sh[lr  ][lc+1]; mn[2]=fminf(mn[2],d); mx[2]=fmaxf(mx[2],d);
            d = c - A.sh[lr+2][lc+1]; mn[3]=fminf(mn[3],d); mx[3]=fmaxf(mx[3],d);
            d = c - A.sh[lr  ][lc+2]; mn[4]=fminf(mn[4],d); mx[4]=fmaxf(mx[4],d);
            d = c - A.sh[lr+2][lc  ]; mn[5]=fminf(mn[5],d); mx[5]=fmaxf(mx[5],d);
            d = c - A.sh[lr+1][lc+2]; mn[6]=fminf(mn[6],d); mx[6]=fmaxf(mx[6],d);
            d = c - A.sh[lr+1][lc  ]; mn[7]=fminf(mn[7],d); mx[7]=fmaxf(mx[7],d);
        }
    }
    #pragma unroll
    for (int off=32; off; off>>=1){
        #pragma unroll
        for (int q=0;q<8;q++){
            mn[q] = fminf(mn[q], __shfl_down(mn[q], off));
            mx[q] = fmaxf(mx[q], __shfl_down(mx[q], off));
        }
    }
    if (lane == 0){
        #pragma unroll
        for (int q=0;q<8;q++){ A.redmn[wv][q]=mn[q]; A.redmx[wv][q]=mx[q]; }
    }
    __syncthreads();
    if (tid < 8){
        pmn[(size_t)blk*8 + tid] = fminf(fminf(A.redmn[0][tid],A.redmn[1][tid]),
                                         fminf(A.redmn[2][tid],A.redmn[3][tid]));
        pmx[(size_t)blk*8 + tid] = fmaxf(fmaxf(A.redmx[0][tid],A.redmx[1][tid]),
                                         fmaxf(A.redmx[2][tid],A.redmx[3][tid]));
    }
}

// ---- Phase B: joint histogram over one contiguous 8(9)-row band ----
// vb 0..511: band chunk c = vb&31 (rows [8c, 8c+8); c==31 gets 9 rows), batch b = vb>>5.
__device__ void phaseB_band(SB& Bm, int vb, const float* __restrict__ s, const float* __restrict__ cl,
                            const float* __restrict__ chp,
                            const float* __restrict__ pmn, const float* __restrict__ pmx,
                            float* __restrict__ hist)
{
    int tid = threadIdx.x, wv = tid >> 6, lane = tid & 63;
    int c = vb & 31, b = vb >> 5;
    int h0 = c*8;
    int nr = (c == 31) ? 9 : 8;

    for (int t = tid; t < 4*64*32; t += 256) Bm.lh[t] = 0.f;

    const float* sb = s + (size_t)b*SBP;
    int total = (nr+2)*260;
    for (int t = tid; t < total; t += 256){
        int lr = t/260, wc2 = t - lr*260;
        Bm.band[lr][wc2] = sb[(size_t)(h0+lr)*SROW + wc2];
    }

    float mnA=INFINITY, mxA=-INFINITY, mnB=INFINITY, mxB=-INFINITY;
    for (int t = lane; t < NT; t += 64){
        const float* pn = pmn + ((size_t)(b*NT + t))*8;
        const float* px = pmx + ((size_t)(b*NT + t))*8;
        mnA = fminf(mnA, pn[2*wv]);   mxA = fmaxf(mxA, px[2*wv]);
        mnB = fminf(mnB, pn[2*wv+1]); mxB = fmaxf(mxB, px[2*wv+1]);
    }
    #pragma unroll
    for (int off=32; off; off>>=1){
        mnA = fminf(mnA, __shfl_down(mnA, off)); mxA = fmaxf(mxA, __shfl_down(mxA, off));
        mnB = fminf(mnB, __shfl_down(mnB, off)); mxB = fmaxf(mxB, __shfl_down(mxB, off));
    }
    mnA = __shfl(mnA, 0); mxA = __shfl(mxA, 0);
    mnB = __shfl(mnB, 0); mxB = __shfl(mxB, 0);
    float lo = cl[0], hi = chp[0];
    float mn0 = fminf(fmaxf(mnA, lo), hi), mx0 = fminf(fmaxf(mxA, lo), hi);
    float mn1 = fminf(fmaxf(mnB, lo), hi), mx1 = fminf(fmaxf(mxB, lo), hi);
    float cd0 = (mx0-mn0)*0.125f;
    float cd1 = (mx1-mn1)*0.125f;
    float m0[9], m1[9];
    #pragma unroll
    for (int i=0;i<9;i++){
        m0[i] = __fadd_rn(__fmul_rn((float)i, cd0), mn0);   // match ref: mul then add, no fma
        m1[i] = __fadd_rn(__fmul_rn((float)i, cd1), mn1);
    }
    int g = b*4 + wv;
    int dh, dw; group_off(wv, dh, dw);
    float* lhg = Bm.lh + wv*2048 + (lane & 31);
    __syncthreads();

    int npx = nr*257;
    for (int p = lane; p < npx; p += 64){
        int lrr = p/257;
        int w = p - lrr*257;
        float cc = Bm.band[lrr+1][w+1];
        float v0 = fminf(fmaxf(cc - Bm.band[lrr+1+dh][w+1+dw], lo), hi);
        float v1 = fminf(fmaxf(cc - Bm.band[lrr+1-dh][w+1-dw], lo), hi);
        unsigned b0=0, b1=0;
        #pragma unroll
        for (int i=0;i<8;i++){
            b0 |= (v0>=m0[i] && v0<=m0[i+1]) ? (1u<<i) : 0u;  // boundary values hit 2 bins, like ref
            b1 |= (v1>=m1[i] && v1<=m1[i+1]) ? (1u<<i) : 0u;
        }
        float pr = v0*v1;
        unsigned bb0=b0;
        while (bb0){
            int i = __ffs(bb0)-1; bb0 &= bb0-1;
            unsigned bb1=b1;
            while (bb1){
                int j = __ffs(bb1)-1; bb1 &= bb1-1;
                atomicAdd(&lhg[(i*8+j)*32], pr);
            }
        }
    }
    __syncthreads();
    float acc = 0.f;
    #pragma unroll
    for (int r=0;r<32;r++) acc += Bm.lh[(wv*64 + lane)*32 + ((lane + r)&31)];
    if (acc != 0.f) atomicAdd(&hist[g*64 + lane], acc);
}

// ---- Phase C: stats preamble + expand + LN + conv folds + output rows ----
// vb 0..511: chunk ch = vb&31 (output rows [8ch, 8ch+8)), batch b = vb>>5.
__device__ void phaseC_block(SC& Cm, int vb, const float* __restrict__ hist,
                    const float* __restrict__ pmn, const float* __restrict__ pmx,
                    const float* __restrict__ cl, const float* __restrict__ chp,
                    const float* __restrict__ we, const float* __restrict__ be,
                    const float* __restrict__ wc, const float* __restrict__ bc,
                    const float* __restrict__ wf, const float* __restrict__ bf,
                    float* __restrict__ out)
{
    int tid = threadIdx.x, wv = tid >> 6, lane = tid & 63;
    int ch = vb & 31, b = vb >> 5;
    if (tid < 144) Cm.wfl[tid] = wf[tid];

    float rmn[8], rmx[8];
    #pragma unroll
    for (int q=0;q<8;q++){ rmn[q]=INFINITY; rmx[q]=-INFINITY; }
    for (int t = tid; t < NT; t += 256){
        const float* pn = pmn + ((size_t)(b*NT + t))*8;
        const float* px = pmx + ((size_t)(b*NT + t))*8;
        #pragma unroll
        for (int q=0;q<8;q++){ rmn[q]=fminf(rmn[q],pn[q]); rmx[q]=fmaxf(rmx[q],px[q]); }
    }
    #pragma unroll
    for (int off=32; off; off>>=1){
        #pragma unroll
        for (int q=0;q<8;q++){
            rmn[q] = fminf(rmn[q], __shfl_down(rmn[q], off));
            rmx[q] = fmaxf(rmx[q], __shfl_down(rmx[q], off));
        }
    }
    if (lane == 0){
        #pragma unroll
        for (int q=0;q<8;q++){ Cm.wred[wv][q]=rmn[q]; Cm.wred[wv][8+q]=rmx[q]; }
    }
    __syncthreads();
    if (tid < 8)
        Cm.gmn[tid] = fminf(fminf(Cm.wred[0][tid],Cm.wred[1][tid]), fminf(Cm.wred[2][tid],Cm.wred[3][tid]));
    else if (tid < 16){
        int q = tid-8;
        Cm.gmx[q] = fmaxf(fmaxf(Cm.wred[0][8+q],Cm.wred[1][8+q]), fmaxf(Cm.wred[2][8+q],Cm.wred[3][8+q]));
    }

    float ps = 0.f;
    for (int t = tid; t < 4096; t += 256) ps += hist[t];
    #pragma unroll
    for (int off=32; off; off>>=1) ps += __shfl_down(ps, off);
    if (lane == 0) Cm.sred[wv] = ps;
    __syncthreads();
    float S = Cm.sred[0]+Cm.sred[1]+Cm.sred[2]+Cm.sred[3];

    int g = b*4 + wv;
    float lo = cl[0], hi = chp[0];
    float mn0 = fminf(fmaxf(Cm.gmn[2*wv  ], lo), hi), mx0 = fminf(fmaxf(Cm.gmx[2*wv  ], lo), hi);
    float mn1 = fminf(fmaxf(Cm.gmn[2*wv+1], lo), hi), mx1 = fminf(fmaxf(Cm.gmx[2*wv+1], lo), hi);
    float lvl0 = __fadd_rn(__fmul_rn(1.0f,(mx0-mn0)*0.125f), mn0);
    float lvl1 = __fadd_rn(__fmul_rn(1.0f,(mx1-mn1)*0.125f), mn1);
    for (int e = lane; e < 3584; e += 64){
        int ij = e/56, o = e - ij*56;
        int i = ij>>3, j = ij&7;
        float f0 = __fmul_rn((float)(i+1), lvl0);
        float f1 = __fmul_rn((float)(j+1), lvl1);
        float f2 = hist[g*64+ij] / S;
        float a = f0*we[o*3+0] + f1*we[o*3+1] + f2*we[o*3+2] + be[o];
        Cm.hloc[wv*3584 + e] = leaky(a);
    }
    float pm = 0.f;
    for (int e = lane; e < 3584; e += 64){
        int o = e%56;
        int lo_ = (32*o+6)/7, hi_ = (32*o+31)/7;
        pm += Cm.hloc[wv*3584+e] * (float)(4*(hi_-lo_+1));
    }
    #pragma unroll
    for (int off=32; off; off>>=1) pm += __shfl_down(pm, off);
    pm = __shfl(pm, 0);
    float mean = pm * (1.0f/65536.0f);
    float pv = 0.f;
    for (int e = lane; e < 3584; e += 64){
        int o = e%56;
        int lo_ = (32*o+6)/7, hi_ = (32*o+31)/7;
        float d = Cm.hloc[wv*3584+e] - mean;
        pv += d*d * (float)(4*(hi_-lo_+1));
    }
    #pragma unroll
    for (int off=32; off; off>>=1) pv += __shfl_down(pv, off);
    pv = __shfl(pv, 0);
    if (lane == 0){
        Cm.gstat[wv*2+0] = mean;
        Cm.gstat[wv*2+1] = 1.0f / sqrtf(pv * (1.0f/65536.0f) + 1e-5f);
    }
    __syncthreads();

    int rm = (2*ch-1 > 0) ? (2*ch-1) : 0;
    int rp = (2*ch+2 < 63) ? (2*ch+2) : 63;
    int ne = (rp-rm+1)*56;
    for (int e = tid; e < ne; e += 256){
        int rr = e/56, sxc = e - rr*56;
        int eg = (rm+rr)*56 + sxc;
        float hn[4];
        #pragma unroll
        for (int k=0;k<4;k++) hn[k] = (Cm.hloc[k*3584+eg] - Cm.gstat[2*k]) * Cm.gstat[2*k+1];
        float w9v[9] = {0,0,0,0,0,0,0,0,0};
        #pragma unroll
        for (int c2=0;c2<16;c2++){
            float hv = bc[c2];
            #pragma unroll
            for (int k=0;k<4;k++) hv += wc[c2*4+k]*hn[k];
            hv = leaky(hv);
            #pragma unroll
            for (int t=0;t<9;t++) w9v[t] += Cm.wfl[c2*9+t]*hv;
        }
        #pragma unroll
        for (int t=0;t<9;t++) Cm.w9l[rr*504 + t*56 + sxc] = w9v[t];
    }
    __syncthreads();

    float bf0 = bf[0];
    int x = tid;
    int sxm = ((x-1)*7) >> 5;
    int sx0 = (x*7) >> 5;
    int sxp = ((x+1)*7) >> 5;
    for (int yo=0; yo<8; ++yo){
        int y = ch*8 + yo;
        float acc = bf0;
        #pragma unroll
        for (int dy=0; dy<3; ++dy){
            int yy = y + dy - 1;
            if ((unsigned)yy >= 256u) continue;
            const float* wr = &Cm.w9l[((yy>>2) - rm)*504 + dy*3*56];
            if (x >= 1)   acc += wr[sxm];
                          acc += wr[56 + sx0];
            if (x <= 254) acc += wr[2*56 + sxp];
        }
        out[((size_t)(b*256 + y))*256 + x] = leaky(acc);
    }
}

// ---- Fused persistent kernel: A (tile loop) -> barrier -> B (vb loop) -> barrier -> C ----
__global__ __launch_bounds__(256, 2) void fused(int nblk, unsigned* __restrict__ bar,
                    const float* __restrict__ x, float* __restrict__ s,
                    float* __restrict__ pmn, float* __restrict__ pmx, float* __restrict__ hist,
                    const float* __restrict__ cl, const float* __restrict__ chp,
                    const float* __restrict__ we, const float* __restrict__ be,
                    const float* __restrict__ wc, const float* __restrict__ bc,
                    const float* __restrict__ wf, const float* __restrict__ bf,
                    float* __restrict__ out)
{
    __shared__ SU sm;
    int bid = blockIdx.x;

    for (int blk = bid; blk < NTILES; blk += nblk){
        __syncthreads();
        phaseA_tile(sm.a, blk, x, s, pmn, pmx, hist);
    }
    grid_barrier(bar, 0, nblk);

    for (int vb = bid; vb < NVB; vb += nblk){
        __syncthreads();
        phaseB_band(sm.b, vb, s, cl, chp, pmn, pmx, hist);
    }
    grid_barrier(bar, 1, nblk);

    for (int vb = bid; vb < NVB; vb += nblk){
        __syncthreads();
        phaseC_block(sm.c, vb, hist, pmn, pmx, cl, chp, we, be, wc, bc, wf, bf, out);
    }
}

extern "C" void kernel_launch(void* const* d_in, const int* in_sizes, int n_in,
                              void* d_out, int out_size, void* d_ws, size_t ws_size,
                              hipStream_t stream){
    const float* x  = (const float*)d_in[0];
    const float* cl = (const float*)d_in[1];
    const float* ch = (const float*)d_in[2];
    const float* we = (const float*)d_in[3];
    const float* be = (const float*)d_in[4];
    const float* wc = (const float*)d_in[5];
    const float* bc = (const float*)d_in[6];
    const float* wf = (const float*)d_in[7];
    const float* bf = (const float*)d_in[8];
    float* out = (float*)d_out;

    float* s = (float*)d_ws;
    size_t off = (size_t)BATCH*SBP;
    float* pmn  = s + off; off += (size_t)BATCH*NT*8;
    float* pmx  = s + off; off += (size_t)BATCH*NT*8;
    float* hist = s + off; off += 4096;
    unsigned* bar = (unsigned*)(s + off); off += 16;

    // Co-residency check: grid must not exceed resident capacity or the barrier deadlocks.
    int perCU = 0;
    hipError_t qe = hipOccupancyMaxActiveBlocksPerMultiprocessor(&perCU, fused, 256, 0);
    int nblk = (qe == hipSuccess && perCU >= 2) ? 512 : 256;

    hipMemsetAsync(bar, 0, 4*sizeof(unsigned), stream);
    fused<<<nblk, 256, 0, stream>>>(nblk, bar, x, s, pmn, pmx, hist,
                                    cl, ch, we, be, wc, bc, wf, bf, out);
}

// Round 5
// 149.001 us; speedup vs baseline: 1.7739x; 1.7739x over previous
//
#include <hip/hip_runtime.h>
#include <stdint.h>
#include <math.h>

#define HH 256
#define WW 256
#define BATCH 16
#define HP 257            // pooled field is 257x257
#define SROW 264          // padded row stride (multiple of 4 -> vec4 rows)
#define SH 259            // padded rows (1 zero row top/bottom)
#define SBP (SH*SROW)     // per-batch padded s size
#define NPART 32          // minmax partial sets per batch (one per k1 band)

// s layout: s[b][r][c], r=0..258, c=0..263. Core: pooled(h,w) at r=h+1, c=w+4.
// Pads: r=0, r=258 full rows zero; cols 0..3 and 261..263 zero for all rows.
// Core cols span 4..260. 16B alignment: row stride 1056B, core col 4 -> +16B.

__device__ __forceinline__ float leaky(float v){ return v >= 0.f ? v : 0.01f*v; }

// group k (0..3) channel-0 offset; channel 1 uses the negation.
__device__ __forceinline__ void group_off(int k, int& dh, int& dw){
    dh = (k == 3) ? 0 : -1;
    dw = (k == 3) ? 1 : (k - 1);
}

// ---- K1: band pool -> s + 8-diff minmax partials. grid (32, BATCH). ----
// Band c: core pooled rows [8c, 8c+nr), nr=8 (c==31: 9). All x reads vec4, one batch.
__global__ __launch_bounds__(256) void k1(const float* __restrict__ x, float* __restrict__ s,
                                          float* __restrict__ pmn, float* __restrict__ pmx,
                                          float* __restrict__ hist){
    __shared__ __align__(16) float xs[12][264];   // X rows h0-2 .. h0+9 (chan-summed, col+4)
    __shared__ __align__(16) float ps[11][264];   // pooled rows h0-1 .. h0+nr (col+4)
    __shared__ float redmn[4][8], redmx[4][8];
    int c = blockIdx.x, b = blockIdx.y;
    int tid = threadIdx.x, wv = tid >> 6, lane = tid & 63;
    int h0 = c*8;
    int nr = (c == 31) ? 9 : 8;

    if (c == 0 && b == 0){
        for (int t = tid; t < 4096; t += 256) hist[t] = 0.f;
    }
    float* sb = s + (size_t)b*SBP;
    // zero pad cols (0..3, 261..263) of this band's core s rows
    for (int t = tid; t < nr*7; t += 256){
        int rr = t/7, k = t%7;
        int col = (k < 4) ? k : (257 + k);      // 0..3, 261..263
        sb[(size_t)(h0+1+rr)*SROW + col] = 0.f;
    }
    if (c == 0){  for (int t = tid; t < SROW; t += 256) sb[t] = 0.f; }
    if (c == 31){ for (int t = tid; t < SROW; t += 256) sb[(size_t)258*SROW + t] = 0.f; }

    // stage channel-summed X band: rows h0-2..h0+9, cols -4..259 (zero pads/OOB), vec4
    const float* xb = x + (size_t)b*3*HH*WW;
    for (int t = tid; t < 12*66; t += 256){
        int i = t/66, q = t - i*66;
        int r = h0 - 2 + i;
        float4 v = make_float4(0.f, 0.f, 0.f, 0.f);
        if (q >= 1 && q <= 64 && (unsigned)r < 256u){
            const float* base = xb + (size_t)r*WW + (q-1)*4;
            float4 a = *(const float4*)(base);
            float4 d = *(const float4*)(base + HH*WW);
            float4 e = *(const float4*)(base + 2*HH*WW);
            v.x = a.x + d.x + e.x;   // keep ref order: c0 + c1 + c2
            v.y = a.y + d.y + e.y;
            v.z = a.z + d.z + e.z;
            v.w = a.w + d.w + e.w;
        }
        *(float4*)&xs[i][q*4] = v;
    }
    __syncthreads();

    // pooled rows j=0..nr+1 (h = h0-1+j); zero outside [0,257)
    int np = (nr+2)*257;
    for (int t = tid; t < np; t += 256){
        int j = t/257, w = t - j*257;
        int h = h0 - 1 + j;
        float v = 0.f;
        if ((unsigned)h < (unsigned)HP)
            v = 0.25f*(xs[j][w+3] + xs[j][w+4] + xs[j+1][w+3] + xs[j+1][w+4]);
        ps[j][w+4] = v;
    }
    for (int t = tid; t < (nr+2)*7; t += 256){
        int j = t/7, k = t%7;
        ps[j][(k < 4) ? k : (257 + k)] = 0.f;   // cols 0..3, 261..263
    }
    __syncthreads();

    float mn[8], mx[8];
    #pragma unroll
    for (int q=0;q<8;q++){ mn[q]=INFINITY; mx[q]=-INFINITY; }
    int nd = nr*257;
    for (int t = tid; t < nd; t += 256){
        int lr = t/257, w = t - lr*257;
        int h = h0 + lr;
        float cv = ps[lr+1][w+4];
        sb[(size_t)(h+1)*SROW + (w+4)] = cv;
        float d;
        d = cv - ps[lr  ][w+3]; mn[0]=fminf(mn[0],d); mx[0]=fmaxf(mx[0],d);  // (-1,-1)
        d = cv - ps[lr+2][w+5]; mn[1]=fminf(mn[1],d); mx[1]=fmaxf(mx[1],d);  // (+1,+1)
        d = cv - ps[lr  ][w+4]; mn[2]=fminf(mn[2],d); mx[2]=fmaxf(mx[2],d);  // (-1, 0)
        d = cv - ps[lr+2][w+4]; mn[3]=fminf(mn[3],d); mx[3]=fmaxf(mx[3],d);  // (+1, 0)
        d = cv - ps[lr  ][w+5]; mn[4]=fminf(mn[4],d); mx[4]=fmaxf(mx[4],d);  // (-1,+1)
        d = cv - ps[lr+2][w+3]; mn[5]=fminf(mn[5],d); mx[5]=fmaxf(mx[5],d);  // (+1,-1)
        d = cv - ps[lr+1][w+5]; mn[6]=fminf(mn[6],d); mx[6]=fmaxf(mx[6],d);  // ( 0,+1)
        d = cv - ps[lr+1][w+3]; mn[7]=fminf(mn[7],d); mx[7]=fmaxf(mx[7],d);  // ( 0,-1)
    }
    #pragma unroll
    for (int off=32; off; off>>=1){
        #pragma unroll
        for (int q=0;q<8;q++){
            mn[q] = fminf(mn[q], __shfl_down(mn[q], off));
            mx[q] = fmaxf(mx[q], __shfl_down(mx[q], off));
        }
    }
    if (lane == 0){
        #pragma unroll
        for (int q=0;q<8;q++){ redmn[wv][q]=mn[q]; redmx[wv][q]=mx[q]; }
    }
    __syncthreads();
    int blk = b*NPART + c;
    if (tid < 8){
        pmn[(size_t)blk*8 + tid] = fminf(fminf(redmn[0][tid],redmn[1][tid]),
                                         fminf(redmn[2][tid],redmn[3][tid]));
        pmx[(size_t)blk*8 + tid] = fmaxf(fmaxf(redmx[0][tid],redmx[1][tid]),
                                         fmaxf(redmx[2][tid],redmx[3][tid]));
    }
}

// ---- K2: joint histogram over 4-row bands staged vec4 in LDS. grid (64, BATCH). ----
__global__ __launch_bounds__(256) void k2(const float* __restrict__ s, const float* __restrict__ cl,
                                          const float* __restrict__ chp,
                                          const float* __restrict__ pmn, const float* __restrict__ pmx,
                                          float* __restrict__ hist){
    __shared__ __align__(16) float lh[4*64*32];   // [group][bin][replica] = 32 KB
    __shared__ __align__(16) float band[7][264];  // s rows h0 .. h0+nr+1
    int c = blockIdx.x, b = blockIdx.y;
    int tid = threadIdx.x, wv = tid >> 6, lane = tid & 63;
    int h0 = c*4;
    int nr = (c == 63) ? 5 : 4;

    float4 z4 = make_float4(0.f,0.f,0.f,0.f);
    float4* lhv = (float4*)lh;
    for (int t = tid; t < 2048; t += 256) lhv[t] = z4;

    // stage band rows (s rows h0..h0+nr+1), 66 vec4 each, all independent
    const float* sb = s + (size_t)b*SBP;
    int tot = (nr+2)*66;
    for (int t = tid; t < tot; t += 256){
        int lr = t/66, q = t - lr*66;
        *(float4*)&band[lr][q*4] = *(const float4*)(sb + (size_t)(h0+lr)*SROW + q*4);
    }

    // reduce this batch+group's minmax partials (channels 2wv, 2wv+1) over 32 sets
    float mnA=INFINITY, mxA=-INFINITY, mnB=INFINITY, mxB=-INFINITY;
    for (int t = lane; t < NPART; t += 64){
        const float* pn = pmn + ((size_t)(b*NPART + t))*8;
        const float* px = pmx + ((size_t)(b*NPART + t))*8;
        mnA = fminf(mnA, pn[2*wv]);   mxA = fmaxf(mxA, px[2*wv]);
        mnB = fminf(mnB, pn[2*wv+1]); mxB = fmaxf(mxB, px[2*wv+1]);
    }
    #pragma unroll
    for (int off=32; off; off>>=1){
        mnA = fminf(mnA, __shfl_down(mnA, off)); mxA = fmaxf(mxA, __shfl_down(mxA, off));
        mnB = fminf(mnB, __shfl_down(mnB, off)); mxB = fmaxf(mxB, __shfl_down(mxB, off));
    }
    mnA = __shfl(mnA, 0); mxA = __shfl(mxA, 0);
    mnB = __shfl(mnB, 0); mxB = __shfl(mxB, 0);
    float lo = cl[0], hi = chp[0];
    float mn0 = fminf(fmaxf(mnA, lo), hi), mx0 = fminf(fmaxf(mxA, lo), hi);
    float mn1 = fminf(fmaxf(mnB, lo), hi), mx1 = fminf(fmaxf(mxB, lo), hi);
    float cd0 = (mx0-mn0)*0.125f;
    float cd1 = (mx1-mn1)*0.125f;
    float m0[9], m1[9];
    #pragma unroll
    for (int i=0;i<9;i++){
        m0[i] = __fadd_rn(__fmul_rn((float)i, cd0), mn0);   // match ref: mul then add, no fma
        m1[i] = __fadd_rn(__fmul_rn((float)i, cd1), mn1);
    }
    int g = b*4 + wv;
    int dh, dw; group_off(wv, dh, dw);
    float* lhg = lh + wv*2048 + (lane & 31);
    __syncthreads();

    int npx = nr*257;
    for (int p = lane; p < npx; p += 64){
        int lrr = p/257;
        int w = p - lrr*257;
        float cc = band[lrr+1][w+4];
        float v0 = fminf(fmaxf(cc - band[lrr+1+dh][w+4+dw], lo), hi);
        float v1 = fminf(fmaxf(cc - band[lrr+1-dh][w+4-dw], lo), hi);
        unsigned b0=0, b1=0;
        #pragma unroll
        for (int i=0;i<8;i++){
            b0 |= (v0>=m0[i] && v0<=m0[i+1]) ? (1u<<i) : 0u;  // boundary values hit 2 bins, like ref
            b1 |= (v1>=m1[i] && v1<=m1[i+1]) ? (1u<<i) : 0u;
        }
        float pr = v0*v1;
        unsigned bb0=b0;
        while (bb0){
            int i = __ffs(bb0)-1; bb0 &= bb0-1;
            unsigned bb1=b1;
            while (bb1){
                int j = __ffs(bb1)-1; bb1 &= bb1-1;
                atomicAdd(&lhg[(i*8+j)*32], pr);
            }
        }
    }
    __syncthreads();
    float acc = 0.f;
    #pragma unroll
    for (int r=0;r<32;r++) acc += lh[(wv*64 + lane)*32 + ((lane + r)&31)];
    if (acc != 0.f) atomicAdd(&hist[g*64 + lane], acc);
}

// ---- K3: stats preamble + expand + LN + conv folds + output rows. grid (32, BATCH). ----
__global__ __launch_bounds__(256) void k3(const float* __restrict__ hist,
                    const float* __restrict__ pmn, const float* __restrict__ pmx,
                    const float* __restrict__ cl, const float* __restrict__ chp,
                    const float* __restrict__ we, const float* __restrict__ be,
                    const float* __restrict__ wc, const float* __restrict__ bc,
                    const float* __restrict__ wf, const float* __restrict__ bf,
                    float* __restrict__ out){
    __shared__ float hloc[4*3584];    // 56 KB
    __shared__ float w9l[4*9*56];
    __shared__ float wfl[144];
    __shared__ float wred[4][16];
    __shared__ float gmn[8], gmx[8];
    __shared__ float gstat[8];
    __shared__ float sred[4];
    int ch = blockIdx.x, b = blockIdx.y;
    int tid = threadIdx.x, wv = tid >> 6, lane = tid & 63;
    if (tid < 144) wfl[tid] = wf[tid];

    float rmn[8], rmx[8];
    #pragma unroll
    for (int q=0;q<8;q++){ rmn[q]=INFINITY; rmx[q]=-INFINITY; }
    for (int t = tid; t < NPART; t += 256){
        const float* pn = pmn + ((size_t)(b*NPART + t))*8;
        const float* px = pmx + ((size_t)(b*NPART + t))*8;
        #pragma unroll
        for (int q=0;q<8;q++){ rmn[q]=fminf(rmn[q],pn[q]); rmx[q]=fmaxf(rmx[q],px[q]); }
    }
    #pragma unroll
    for (int off=32; off; off>>=1){
        #pragma unroll
        for (int q=0;q<8;q++){
            rmn[q] = fminf(rmn[q], __shfl_down(rmn[q], off));
            rmx[q] = fmaxf(rmx[q], __shfl_down(rmx[q], off));
        }
    }
    if (lane == 0){
        #pragma unroll
        for (int q=0;q<8;q++){ wred[wv][q]=rmn[q]; wred[wv][8+q]=rmx[q]; }
    }
    __syncthreads();
    if (tid < 8)
        gmn[tid] = fminf(fminf(wred[0][tid],wred[1][tid]), fminf(wred[2][tid],wred[3][tid]));
    else if (tid < 16){
        int q = tid-8;
        gmx[q] = fmaxf(fmaxf(wred[0][8+q],wred[1][8+q]), fmaxf(wred[2][8+q],wred[3][8+q]));
    }

    float ps = 0.f;
    for (int t = tid; t < 4096; t += 256) ps += hist[t];
    #pragma unroll
    for (int off=32; off; off>>=1) ps += __shfl_down(ps, off);
    if (lane == 0) sred[wv] = ps;
    __syncthreads();
    float S = sred[0]+sred[1]+sred[2]+sred[3];

    int g = b*4 + wv;
    float lo = cl[0], hi = chp[0];
    float mn0 = fminf(fmaxf(gmn[2*wv  ], lo), hi), mx0 = fminf(fmaxf(gmx[2*wv  ], lo), hi);
    float mn1 = fminf(fmaxf(gmn[2*wv+1], lo), hi), mx1 = fminf(fmaxf(gmx[2*wv+1], lo), hi);
    float lvl0 = __fadd_rn(__fmul_rn(1.0f,(mx0-mn0)*0.125f), mn0);
    float lvl1 = __fadd_rn(__fmul_rn(1.0f,(mx1-mn1)*0.125f), mn1);
    for (int e = lane; e < 3584; e += 64){
        int ij = e/56, o = e - ij*56;
        int i = ij>>3, j = ij&7;
        float f0 = __fmul_rn((float)(i+1), lvl0);
        float f1 = __fmul_rn((float)(j+1), lvl1);
        float f2 = hist[g*64+ij] / S;
        float a = f0*we[o*3+0] + f1*we[o*3+1] + f2*we[o*3+2] + be[o];
        hloc[wv*3584 + e] = leaky(a);
    }
    float pm = 0.f;
    for (int e = lane; e < 3584; e += 64){
        int o = e%56;
        int lo_ = (32*o+6)/7, hi_ = (32*o+31)/7;
        pm += hloc[wv*3584+e] * (float)(4*(hi_-lo_+1));
    }
    #pragma unroll
    for (int off=32; off; off>>=1) pm += __shfl_down(pm, off);
    pm = __shfl(pm, 0);
    float mean = pm * (1.0f/65536.0f);
    float pv = 0.f;
    for (int e = lane; e < 3584; e += 64){
        int o = e%56;
        int lo_ = (32*o+6)/7, hi_ = (32*o+31)/7;
        float d = hloc[wv*3584+e] - mean;
        pv += d*d * (float)(4*(hi_-lo_+1));
    }
    #pragma unroll
    for (int off=32; off; off>>=1) pv += __shfl_down(pv, off);
    pv = __shfl(pv, 0);
    if (lane == 0){
        gstat[wv*2+0] = mean;
        gstat[wv*2+1] = 1.0f / sqrtf(pv * (1.0f/65536.0f) + 1e-5f);
    }
    __syncthreads();

    int rm = (2*ch-1 > 0) ? (2*ch-1) : 0;
    int rp = (2*ch+2 < 63) ? (2*ch+2) : 63;
    int ne = (rp-rm+1)*56;
    for (int e = tid; e < ne; e += 256){
        int rr = e/56, sxc = e - rr*56;
        int eg = (rm+rr)*56 + sxc;
        float hn[4];
        #pragma unroll
        for (int k=0;k<4;k++) hn[k] = (hloc[k*3584+eg] - gstat[2*k]) * gstat[2*k+1];
        float w9v[9] = {0,0,0,0,0,0,0,0,0};
        #pragma unroll
        for (int c2=0;c2<16;c2++){
            float hv = bc[c2];
            #pragma unroll
            for (int k=0;k<4;k++) hv += wc[c2*4+k]*hn[k];
            hv = leaky(hv);
            #pragma unroll
            for (int t=0;t<9;t++) w9v[t] += wfl[c2*9+t]*hv;
        }
        #pragma unroll
        for (int t=0;t<9;t++) w9l[rr*504 + t*56 + sxc] = w9v[t];
    }
    __syncthreads();

    float bf0 = bf[0];
    int x = tid;
    int sxm = ((x-1)*7) >> 5;
    int sx0 = (x*7) >> 5;
    int sxp = ((x+1)*7) >> 5;
    for (int yo=0; yo<8; ++yo){
        int y = ch*8 + yo;
        float acc = bf0;
        #pragma unroll
        for (int dy=0; dy<3; ++dy){
            int yy = y + dy - 1;
            if ((unsigned)yy >= 256u) continue;
            const float* wr = &w9l[((yy>>2) - rm)*504 + dy*3*56];
            if (x >= 1)   acc += wr[sxm];
                          acc += wr[56 + sx0];
            if (x <= 254) acc += wr[2*56 + sxp];
        }
        out[((size_t)(b*256 + y))*256 + x] = leaky(acc);
    }
}

extern "C" void kernel_launch(void* const* d_in, const int* in_sizes, int n_in,
                              void* d_out, int out_size, void* d_ws, size_t ws_size,
                              hipStream_t stream){
    const float* x  = (const float*)d_in[0];
    const float* cl = (const float*)d_in[1];
    const float* ch = (const float*)d_in[2];
    const float* we = (const float*)d_in[3];
    const float* be = (const float*)d_in[4];
    const float* wc = (const float*)d_in[5];
    const float* bc = (const float*)d_in[6];
    const float* wf = (const float*)d_in[7];
    const float* bf = (const float*)d_in[8];
    float* out = (float*)d_out;

    float* s = (float*)d_ws;
    size_t off = (size_t)BATCH*SBP;
    float* pmn  = s + off; off += (size_t)BATCH*NPART*8;
    float* pmx  = s + off; off += (size_t)BATCH*NPART*8;
    float* hist = s + off; off += 4096;

    k1<<<dim3(32,BATCH), 256, 0, stream>>>(x, s, pmn, pmx, hist);
    k2<<<dim3(64,BATCH), 256, 0, stream>>>(s, cl, ch, pmn, pmx, hist);
    k3<<<dim3(32,BATCH), 256, 0, stream>>>(hist, pmn, pmx, cl, ch, we, be, wc, bc, wf, bf, out);
}